// Round 7
// baseline (332.812 us; speedup 1.0000x reference)
//
#include <hip/hip_runtime.h>
#include <hip/hip_bf16.h>
#include <math.h>

// Sizes fixed by the problem
#define NB 8
#define NC 64
#define NA 32
#define NN 4096
#define NWAVE 8     // waves per block in rsum/alpha kernels

typedef __attribute__((ext_vector_type(8))) short bf16x8;
typedef __attribute__((ext_vector_type(4))) float f32x4;

__device__ inline ushort f2bf(float f) {
  union { float f; unsigned u; } v; v.f = f;
  unsigned r = v.u + 0x7fffu + ((v.u >> 16) & 1u);
  return (ushort)(r >> 16);
}

__device__ inline uint2 packbf(const f32x4 p) {
  uint2 q;
  q.x = (uint)f2bf(p[0]) | ((uint)f2bf(p[1]) << 16);
  q.y = (uint)f2bf(p[2]) | ((uint)f2bf(p[3]) << 16);
  return q;
}

// ---------------------------------------------------------------------------
// Kernel 1: g = (Wg@x + bg) * log2(e)  [folded so scores feed exp2 directly],
//           hq = Wh@x + bh.
// Writes bf16: gT[b][n][a], hqT[b][n][a]  (K=a contiguous for MFMA frags)
// and xfb[b][c][n] = bf16(x).
// ---------------------------------------------------------------------------
__global__ __launch_bounds__(256) void prep_kernel(
    const float* __restrict__ x, const float* __restrict__ Wg, const float* __restrict__ bg,
    const float* __restrict__ Wh, const float* __restrict__ bh,
    ushort* __restrict__ gT, ushort* __restrict__ hqT, ushort* __restrict__ xfb)
{
  __shared__ float wg_s[NA * NC];
  __shared__ float wh_s[NA * NC];
  const int t = threadIdx.x;
  for (int i = t; i < NA * NC; i += 256) { wg_s[i] = Wg[i]; wh_s[i] = Wh[i]; }
  __syncthreads();

  const int gid = blockIdx.x * 256 + t;
  const int b = gid >> 12;          // / NN
  const int n = gid & (NN - 1);
  const float* xb = x + (size_t)b * NC * NN + n;

  float accg[NA], acch[NA];
#pragma unroll
  for (int a = 0; a < NA; ++a) { accg[a] = 0.f; acch[a] = 0.f; }

  for (int c4 = 0; c4 < NC / 4; ++c4) {
    const float xv0 = xb[(size_t)(c4 * 4 + 0) * NN];
    const float xv1 = xb[(size_t)(c4 * 4 + 1) * NN];
    const float xv2 = xb[(size_t)(c4 * 4 + 2) * NN];
    const float xv3 = xb[(size_t)(c4 * 4 + 3) * NN];
    const size_t xo = ((size_t)b * NC + c4 * 4) * NN + n;
    xfb[xo]          = f2bf(xv0);
    xfb[xo + NN]     = f2bf(xv1);
    xfb[xo + 2 * NN] = f2bf(xv2);
    xfb[xo + 3 * NN] = f2bf(xv3);
#pragma unroll
    for (int a = 0; a < NA; ++a) {
      const float4 wg4 = *(const float4*)&wg_s[a * NC + c4 * 4];
      const float4 wh4 = *(const float4*)&wh_s[a * NC + c4 * 4];
      accg[a] += wg4.x * xv0 + wg4.y * xv1 + wg4.z * xv2 + wg4.w * xv3;
      acch[a] += wh4.x * xv0 + wh4.y * xv1 + wh4.z * xv2 + wh4.w * xv3;
    }
  }

  const float LOG2E = 1.44269504088896340736f;
  ushort og[NA], oh[NA];
#pragma unroll
  for (int a = 0; a < NA; ++a) {
    og[a] = f2bf((accg[a] + bg[a]) * LOG2E);   // fold log2(e) into g
    oh[a] = f2bf(acch[a] + bh[a]);
  }
  const size_t o = ((size_t)b * NN + n) * NA;
#pragma unroll
  for (int k = 0; k < 4; ++k) {
    uint4 vg, vh;
    vg.x = (uint)og[k*8+0] | ((uint)og[k*8+1] << 16);
    vg.y = (uint)og[k*8+2] | ((uint)og[k*8+3] << 16);
    vg.z = (uint)og[k*8+4] | ((uint)og[k*8+5] << 16);
    vg.w = (uint)og[k*8+6] | ((uint)og[k*8+7] << 16);
    vh.x = (uint)oh[k*8+0] | ((uint)oh[k*8+1] << 16);
    vh.y = (uint)oh[k*8+2] | ((uint)oh[k*8+3] << 16);
    vh.z = (uint)oh[k*8+4] | ((uint)oh[k*8+5] << 16);
    vh.w = (uint)oh[k*8+6] | ((uint)oh[k*8+7] << 16);
    *(uint4*)(gT  + o + k * 8) = vg;
    *(uint4*)(hqT + o + k * 8) = vh;
  }
}

// ---------------------------------------------------------------------------
// Kernel 2 (rsum): per (b, 32-row n-tile): row sums of e=exp2(scores) and
// r-GEMM with UNNORMALIZED e (normalization folded into epilogue scale).
// NO large global stores -> loop is loads+compute only (no vmcnt FIFO poison).
// Writes: out = relu(r*Linv + x)  and  Linv -> alpha[b][n][0] (scratch slot,
// overwritten later by alpha_kernel).
// scores(transposed) = mfma(A=hq, B=g): lane=(m=lh*4+r, n=lm).
// ---------------------------------------------------------------------------
__global__ __launch_bounds__(512, 4) void rsum_kernel(
    const ushort* __restrict__ gT, const ushort* __restrict__ hqT,
    const ushort* __restrict__ xfb, const float* __restrict__ x,
    float* __restrict__ outp, float* __restrict__ alpha)
{
  __shared__ ushort pbuf[NWAVE][32][36];  // per-wave e staging (bf16)
  __shared__ float rtile[32][65];         // block r accumulator [n][c]
  __shared__ float Lp[NWAVE][32];         // per-wave partial row sums
  __shared__ float LinvS[32];             // block 1/rowsum

  const int tid = threadIdx.x;
  const int l  = tid & 63;
  const int w  = tid >> 6;
  const int lm = l & 15;
  const int lh = l >> 4;

  const int wgid = (blockIdx.x & 7) * 128 + (blockIdx.x >> 3);  // XCD swizzle
  const int b  = wgid >> 7;
  const int n0 = (wgid & 127) << 5;

  const ushort* gB = gT  + (size_t)b * NN * NA;
  const ushort* hB = hqT + (size_t)b * NN * NA;
  const ushort* xB = xfb + (size_t)b * NC * NN;

  bf16x8 gb0 = *(const bf16x8*)(gB + (size_t)(n0 + lm) * NA + lh * 8);
  bf16x8 gb1 = *(const bf16x8*)(gB + (size_t)(n0 + 16 + lm) * NA + lh * 8);
  const int mfirst = w << 9;
  bf16x8 ha0 = *(const bf16x8*)(hB + (size_t)(mfirst + lm) * NA + lh * 8);
  bf16x8 ha1 = *(const bf16x8*)(hB + (size_t)(mfirst + 16 + lm) * NA + lh * 8);

  float* rflat = &rtile[0][0];
  for (int i = tid; i < 32 * 65; i += 512) rflat[i] = 0.f;

  const f32x4 zz = {0.f, 0.f, 0.f, 0.f};
  f32x4 racc[2][4];
#pragma unroll
  for (int gi = 0; gi < 2; ++gi)
#pragma unroll
    for (int ci = 0; ci < 4; ++ci) racc[gi][ci] = zz;

  float sume0 = 0.f, sume1 = 0.f;

  for (int mc = 0; mc < 16; ++mc) {
    const int m0 = (w << 9) + (mc << 5);
    const int m1 = (w << 9) + (((mc + 1) & 15) << 5);
    // all loads issued up front (loop has NO stores -> waits never stall on stores)
    const bf16x8 na0 = *(const bf16x8*)(hB + (size_t)(m1 + lm) * NA + lh * 8);
    const bf16x8 na1 = *(const bf16x8*)(hB + (size_t)(m1 + 16 + lm) * NA + lh * 8);
    bf16x8 xv[4];
#pragma unroll
    for (int ci = 0; ci < 4; ++ci)
      xv[ci] = *(const bf16x8*)(xB + (size_t)(ci * 16 + lm) * NN + m0 + lh * 8);

    const f32x4 s00 = __builtin_amdgcn_mfma_f32_16x16x32_bf16(ha0, gb0, zz, 0, 0, 0);
    const f32x4 s10 = __builtin_amdgcn_mfma_f32_16x16x32_bf16(ha1, gb0, zz, 0, 0, 0);
    const f32x4 s01 = __builtin_amdgcn_mfma_f32_16x16x32_bf16(ha0, gb1, zz, 0, 0, 0);
    const f32x4 s11 = __builtin_amdgcn_mfma_f32_16x16x32_bf16(ha1, gb1, zz, 0, 0, 0);

    f32x4 e00, e10, e01, e11;
#pragma unroll
    for (int r = 0; r < 4; ++r) {
      e00[r] = exp2f(s00[r]);
      e10[r] = exp2f(s10[r]);
      e01[r] = exp2f(s01[r]);
      e11[r] = exp2f(s11[r]);
      sume0 += e00[r] + e10[r];
      sume1 += e01[r] + e11[r];
    }

    // stage e (bf16, unnormalized) into this wave's private LDS region
    *(uint2*)&pbuf[w][lm][lh * 4]           = packbf(e00);
    *(uint2*)&pbuf[w][lm][16 + lh * 4]      = packbf(e10);
    *(uint2*)&pbuf[w][16 + lm][lh * 4]      = packbf(e01);
    *(uint2*)&pbuf[w][16 + lm][16 + lh * 4] = packbf(e11);

    // A-frags: e[n=lm(+16)][m = lh*8 .. +7]
    union UB { uint4 u; bf16x8 v; } ua, ub;
    {
      const uint2 a0 = *(const uint2*)&pbuf[w][lm][lh * 8];
      const uint2 a1 = *(const uint2*)&pbuf[w][lm][lh * 8 + 4];
      ua.u = make_uint4(a0.x, a0.y, a1.x, a1.y);
      const uint2 b0 = *(const uint2*)&pbuf[w][16 + lm][lh * 8];
      const uint2 b1 = *(const uint2*)&pbuf[w][16 + lm][lh * 8 + 4];
      ub.u = make_uint4(b0.x, b0.y, b1.x, b1.y);
    }

#pragma unroll
    for (int ci = 0; ci < 4; ++ci) {
      racc[0][ci] = __builtin_amdgcn_mfma_f32_16x16x32_bf16(ua.v, xv[ci], racc[0][ci], 0, 0, 0);
      racc[1][ci] = __builtin_amdgcn_mfma_f32_16x16x32_bf16(ub.v, xv[ci], racc[1][ci], 0, 0, 0);
    }
    ha0 = na0; ha1 = na1;
  }

  // row-sum reduce: lanes lh=0..3 partition m
  sume0 += __shfl_xor(sume0, 16); sume0 += __shfl_xor(sume0, 32);
  sume1 += __shfl_xor(sume1, 16); sume1 += __shfl_xor(sume1, 32);
  if (l < 16) { Lp[w][l] = sume0; Lp[w][16 + l] = sume1; }
  __syncthreads();

  // block-combined 1/L; also publish Linv to alpha[b][n][0] for alpha_kernel
  if (tid < 32) {
    float s = 0.f;
#pragma unroll
    for (int ww = 0; ww < NWAVE; ++ww) s += Lp[ww][tid];
    const float li = 1.0f / s;
    LinvS[tid] = li;
    alpha[((size_t)b * NN + n0 + tid) * NN] = li;
  }

  // reduce partial r across waves
#pragma unroll
  for (int gi = 0; gi < 2; ++gi)
#pragma unroll
    for (int ci = 0; ci < 4; ++ci)
#pragma unroll
      for (int r = 0; r < 4; ++r)
        atomicAdd(&rtile[gi * 16 + lh * 4 + r][ci * 16 + lm], racc[gi][ci][r]);
  __syncthreads();

  // epilogue: out[b][c][n] = relu(r*Linv + x), coalesced float4
  const int c  = tid >> 3;
  const int j4 = (tid & 7) << 2;
  f32x4 v;
#pragma unroll
  for (int k = 0; k < 4; ++k) v[k] = rtile[j4 + k][c] * LinvS[j4 + k];
  const size_t oo = ((size_t)b * NC + c) * NN + n0 + j4;
  const f32x4 xr = *(const f32x4*)(x + oo);
#pragma unroll
  for (int k = 0; k < 4; ++k) {
    const float t = v[k] + xr[k];
    v[k] = t > 0.f ? t : 0.f;
  }
  __builtin_nontemporal_store(v, (f32x4*)(outp + oo));
}

// ---------------------------------------------------------------------------
// Kernel 3 (alpha): pure streaming producer. Per (b, 32-row n-tile), wave w
// owns m in [w*512, w*512+512). Reads Linv from alpha[b][n][0] (then
// overwrites it). Per iter: prefetch loads FIRST, then MFMA, exp2*Linv,
// 4 plain f32x4 stores (fire-and-forget; no subsequent op waits on them,
// and loads precede stores in FIFO order so vmcnt waits skip the stores).
// No LDS, no barriers in the loop, lean VGPR -> high occupancy.
// ---------------------------------------------------------------------------
__global__ __launch_bounds__(512, 4) void alpha_kernel(
    const ushort* __restrict__ gT, const ushort* __restrict__ hqT,
    float* __restrict__ alpha)
{
  const int tid = threadIdx.x;
  const int l  = tid & 63;
  const int w  = tid >> 6;
  const int lm = l & 15;
  const int lh = l >> 4;

  const int wgid = (blockIdx.x & 7) * 128 + (blockIdx.x >> 3);  // XCD swizzle
  const int b  = wgid >> 7;
  const int n0 = (wgid & 127) << 5;

  const ushort* gB = gT  + (size_t)b * NN * NA;
  const ushort* hB = hqT + (size_t)b * NN * NA;
  float* aB = alpha + ((size_t)b * NN + n0) * NN;

  // read the Linv scratch (column 0) BEFORE anyone overwrites it
  const float Linv0 = aB[(size_t)lm * NN];
  const float Linv1 = aB[(size_t)(16 + lm) * NN];

  bf16x8 gb0 = *(const bf16x8*)(gB + (size_t)(n0 + lm) * NA + lh * 8);
  bf16x8 gb1 = *(const bf16x8*)(gB + (size_t)(n0 + 16 + lm) * NA + lh * 8);
  const int mfirst = w << 9;
  bf16x8 ha0 = *(const bf16x8*)(hB + (size_t)(mfirst + lm) * NA + lh * 8);
  bf16x8 ha1 = *(const bf16x8*)(hB + (size_t)(mfirst + 16 + lm) * NA + lh * 8);

  __syncthreads();   // all Linv reads complete before wave 0's first store

  const f32x4 zz = {0.f, 0.f, 0.f, 0.f};

  for (int mc = 0; mc < 16; ++mc) {
    const int m0 = (w << 9) + (mc << 5);
    const int m1 = (w << 9) + (((mc + 1) & 15) << 5);
    // prefetch loads FIRST (older than this iter's stores in the vmcnt FIFO)
    const bf16x8 na0 = *(const bf16x8*)(hB + (size_t)(m1 + lm) * NA + lh * 8);
    const bf16x8 na1 = *(const bf16x8*)(hB + (size_t)(m1 + 16 + lm) * NA + lh * 8);

    const f32x4 s00 = __builtin_amdgcn_mfma_f32_16x16x32_bf16(ha0, gb0, zz, 0, 0, 0);
    const f32x4 s10 = __builtin_amdgcn_mfma_f32_16x16x32_bf16(ha1, gb0, zz, 0, 0, 0);
    const f32x4 s01 = __builtin_amdgcn_mfma_f32_16x16x32_bf16(ha0, gb1, zz, 0, 0, 0);
    const f32x4 s11 = __builtin_amdgcn_mfma_f32_16x16x32_bf16(ha1, gb1, zz, 0, 0, 0);

    f32x4 p00, p10, p01, p11;
#pragma unroll
    for (int r = 0; r < 4; ++r) {
      p00[r] = exp2f(s00[r]) * Linv0;
      p10[r] = exp2f(s10[r]) * Linv0;
      p01[r] = exp2f(s01[r]) * Linv1;
      p11[r] = exp2f(s11[r]) * Linv1;
    }

    // alpha[n][m]: plain stores; L2 write-back merges 64B halves into lines
    *(f32x4*)(aB + (size_t)lm * NN        + m0 + lh * 4)      = p00;
    *(f32x4*)(aB + (size_t)lm * NN        + m0 + 16 + lh * 4) = p10;
    *(f32x4*)(aB + (size_t)(16 + lm) * NN + m0 + lh * 4)      = p01;
    *(f32x4*)(aB + (size_t)(16 + lm) * NN + m0 + 16 + lh * 4) = p11;

    ha0 = na0; ha1 = na1;
  }
}

// ---------------------------------------------------------------------------
extern "C" void kernel_launch(void* const* d_in, const int* in_sizes, int n_in,
                              void* d_out, int out_size, void* d_ws, size_t ws_size,
                              hipStream_t stream) {
  const float* x  = (const float*)d_in[0];
  const float* Wg = (const float*)d_in[1];
  const float* bg = (const float*)d_in[2];
  const float* Wh = (const float*)d_in[3];
  const float* bh = (const float*)d_in[4];

  float* outp  = (float*)d_out;
  float* alpha = outp + (size_t)NB * NC * NN;   // outputs: relu(r) then alpha

  // workspace: gT (2MB) | hqT (2MB) | xfb (4MB)
  ushort* gT  = (ushort*)d_ws;
  ushort* hqT = gT + (size_t)NB * NN * NA;
  ushort* xfb = hqT + (size_t)NB * NN * NA;

  prep_kernel<<<NB * NN / 256, 256, 0, stream>>>(x, Wg, bg, Wh, bh, gT, hqT, xfb);
  rsum_kernel<<<NB * (NN / 32), 512, 0, stream>>>(gT, hqT, xfb, x, outp, alpha);
  alpha_kernel<<<NB * (NN / 32), 512, 0, stream>>>(gT, hqT, alpha);
}

// Round 8
// 260.531 us; speedup vs baseline: 1.2774x; 1.2774x over previous
//
#include <hip/hip_runtime.h>
#include <hip/hip_bf16.h>
#include <math.h>

// Sizes fixed by the problem
#define NB 8
#define NC 64
#define NA 32
#define NN 4096
#define NWAVE 8     // waves per block
#define PSTRIDE 260 // pstage row stride (floats); 1040B rows, 16B-aligned

typedef __attribute__((ext_vector_type(8))) short bf16x8;
typedef __attribute__((ext_vector_type(4))) float f32x4;

__device__ inline ushort f2bf(float f) {
  union { float f; unsigned u; } v; v.f = f;
  unsigned r = v.u + 0x7fffu + ((v.u >> 16) & 1u);
  return (ushort)(r >> 16);
}

__device__ inline uint2 packbf(const f32x4 p) {
  uint2 q;
  q.x = (uint)f2bf(p[0]) | ((uint)f2bf(p[1]) << 16);
  q.y = (uint)f2bf(p[2]) | ((uint)f2bf(p[3]) << 16);
  return q;
}

// ---------------------------------------------------------------------------
// Kernel 1: g = (Wg@x + bg) * log2(e), hq = Wh@x + bh.  bf16 outputs:
// gT[b][n][a], hqT[b][n][a] (K=a contiguous), xfb[b][c][n] = bf16(x).
// ---------------------------------------------------------------------------
__global__ __launch_bounds__(256) void prep_kernel(
    const float* __restrict__ x, const float* __restrict__ Wg, const float* __restrict__ bg,
    const float* __restrict__ Wh, const float* __restrict__ bh,
    ushort* __restrict__ gT, ushort* __restrict__ hqT, ushort* __restrict__ xfb)
{
  __shared__ float wg_s[NA * NC];
  __shared__ float wh_s[NA * NC];
  const int t = threadIdx.x;
  for (int i = t; i < NA * NC; i += 256) { wg_s[i] = Wg[i]; wh_s[i] = Wh[i]; }
  __syncthreads();

  const int gid = blockIdx.x * 256 + t;
  const int b = gid >> 12;
  const int n = gid & (NN - 1);
  const float* xb = x + (size_t)b * NC * NN + n;

  float accg[NA], acch[NA];
#pragma unroll
  for (int a = 0; a < NA; ++a) { accg[a] = 0.f; acch[a] = 0.f; }

  for (int c4 = 0; c4 < NC / 4; ++c4) {
    const float xv0 = xb[(size_t)(c4 * 4 + 0) * NN];
    const float xv1 = xb[(size_t)(c4 * 4 + 1) * NN];
    const float xv2 = xb[(size_t)(c4 * 4 + 2) * NN];
    const float xv3 = xb[(size_t)(c4 * 4 + 3) * NN];
    const size_t xo = ((size_t)b * NC + c4 * 4) * NN + n;
    xfb[xo]          = f2bf(xv0);
    xfb[xo + NN]     = f2bf(xv1);
    xfb[xo + 2 * NN] = f2bf(xv2);
    xfb[xo + 3 * NN] = f2bf(xv3);
#pragma unroll
    for (int a = 0; a < NA; ++a) {
      const float4 wg4 = *(const float4*)&wg_s[a * NC + c4 * 4];
      const float4 wh4 = *(const float4*)&wh_s[a * NC + c4 * 4];
      accg[a] += wg4.x * xv0 + wg4.y * xv1 + wg4.z * xv2 + wg4.w * xv3;
      acch[a] += wh4.x * xv0 + wh4.y * xv1 + wh4.z * xv2 + wh4.w * xv3;
    }
  }

  const float LOG2E = 1.44269504088896340736f;
  ushort og[NA], oh[NA];
#pragma unroll
  for (int a = 0; a < NA; ++a) {
    og[a] = f2bf((accg[a] + bg[a]) * LOG2E);
    oh[a] = f2bf(acch[a] + bh[a]);
  }
  const size_t o = ((size_t)b * NN + n) * NA;
#pragma unroll
  for (int k = 0; k < 4; ++k) {
    uint4 vg, vh;
    vg.x = (uint)og[k*8+0] | ((uint)og[k*8+1] << 16);
    vg.y = (uint)og[k*8+2] | ((uint)og[k*8+3] << 16);
    vg.z = (uint)og[k*8+4] | ((uint)og[k*8+5] << 16);
    vg.w = (uint)og[k*8+6] | ((uint)og[k*8+7] << 16);
    vh.x = (uint)oh[k*8+0] | ((uint)oh[k*8+1] << 16);
    vh.y = (uint)oh[k*8+2] | ((uint)oh[k*8+3] << 16);
    vh.z = (uint)oh[k*8+4] | ((uint)oh[k*8+5] << 16);
    vh.w = (uint)oh[k*8+6] | ((uint)oh[k*8+7] << 16);
    *(uint4*)(gT  + o + k * 8) = vg;
    *(uint4*)(hqT + o + k * 8) = vh;
  }
}

// ---------------------------------------------------------------------------
// Kernel 2: block = (b, 32-row n-tile), XCD-swizzled (one batch per XCD).
// scores(transposed) = mfma(A=hq, B=g): lane=(m=lh*4+r, n=lm).
// PHASE 1 (loads-only loop): e = exp2(s); row sums; r-GEMM with UNNORMALIZED
//   e via per-wave-private LDS staging (no barriers, no global stores).
//   Epilogue: block reduce, Linv; out = relu(r*Linv + x) (NT).
// PHASE 2 (lean alpha producer): s' = mfma(hq, g, C=log2(Linv)) so
//   p = exp2(s') directly; stage block-wide 32n x 256m f32 window in dbuf
//   LDS; sync via raw "lgkmcnt(0); s_barrier" (NO vmcnt drain); drain with
//   4 PLAIN 1KB-contiguous stores per wave (full-line coverage -> no RFO,
//   L2 write-back streams like the fill kernel).
// ---------------------------------------------------------------------------
__global__ __launch_bounds__(512, 4) void attn_kernel(
    const ushort* __restrict__ gT, const ushort* __restrict__ hqT,
    const ushort* __restrict__ xfb, const float* __restrict__ x,
    float* __restrict__ outp, float* __restrict__ alpha)
{
  __shared__ float pstage[2][32][PSTRIDE];  // phase-2 staging (66.6 KB)
  __shared__ float rtile[32][65];           // block r accumulator [n][c]
  __shared__ float Lp[NWAVE][32];           // per-wave partial row sums
  __shared__ float LinvS[32];               // block 1/rowsum
  // phase-1 per-wave e staging aliases the (unused-in-phase-1) pstage memory
  ushort (*pbuf)[32][36] = reinterpret_cast<ushort (*)[32][36]>(&pstage[0][0][0]);

  const int tid = threadIdx.x;
  const int l  = tid & 63;
  const int w  = tid >> 6;
  const int lm = l & 15;
  const int lh = l >> 4;

  // XCD-aware swizzle: grid=1024, 8 XCDs -> contiguous 128 blocks per XCD
  const int wgid = (blockIdx.x & 7) * 128 + (blockIdx.x >> 3);
  const int b  = wgid >> 7;
  const int n0 = (wgid & 127) << 5;

  const ushort* gB = gT  + (size_t)b * NN * NA;
  const ushort* hB = hqT + (size_t)b * NN * NA;
  const ushort* xB = xfb + (size_t)b * NC * NN;

  bf16x8 gb0 = *(const bf16x8*)(gB + (size_t)(n0 + lm) * NA + lh * 8);
  bf16x8 gb1 = *(const bf16x8*)(gB + (size_t)(n0 + 16 + lm) * NA + lh * 8);
  const int mfirst = w << 9;
  bf16x8 ha0 = *(const bf16x8*)(hB + (size_t)(mfirst + lm) * NA + lh * 8);
  bf16x8 ha1 = *(const bf16x8*)(hB + (size_t)(mfirst + 16 + lm) * NA + lh * 8);

  float* rflat = &rtile[0][0];
  for (int i = tid; i < 32 * 65; i += 512) rflat[i] = 0.f;

  const f32x4 zz = {0.f, 0.f, 0.f, 0.f};
  f32x4 racc[2][4];
#pragma unroll
  for (int gi = 0; gi < 2; ++gi)
#pragma unroll
    for (int ci = 0; ci < 4; ++ci) racc[gi][ci] = zz;

  // ---- Phase 1: row sums + r-GEMM with unnormalized e (no stores) -------
  float sume0 = 0.f, sume1 = 0.f;

  for (int mc = 0; mc < 16; ++mc) {
    const int m0 = (w << 9) + (mc << 5);
    const int m1 = (w << 9) + (((mc + 1) & 15) << 5);
    // ALL global loads at top of body; loop has no stores at all
    const bf16x8 na0 = *(const bf16x8*)(hB + (size_t)(m1 + lm) * NA + lh * 8);
    const bf16x8 na1 = *(const bf16x8*)(hB + (size_t)(m1 + 16 + lm) * NA + lh * 8);
    bf16x8 xv[4];
#pragma unroll
    for (int ci = 0; ci < 4; ++ci)
      xv[ci] = *(const bf16x8*)(xB + (size_t)(ci * 16 + lm) * NN + m0 + lh * 8);

    const f32x4 s00 = __builtin_amdgcn_mfma_f32_16x16x32_bf16(ha0, gb0, zz, 0, 0, 0);
    const f32x4 s10 = __builtin_amdgcn_mfma_f32_16x16x32_bf16(ha1, gb0, zz, 0, 0, 0);
    const f32x4 s01 = __builtin_amdgcn_mfma_f32_16x16x32_bf16(ha0, gb1, zz, 0, 0, 0);
    const f32x4 s11 = __builtin_amdgcn_mfma_f32_16x16x32_bf16(ha1, gb1, zz, 0, 0, 0);

    f32x4 e00, e10, e01, e11;
#pragma unroll
    for (int r = 0; r < 4; ++r) {
      e00[r] = exp2f(s00[r]);
      e10[r] = exp2f(s10[r]);
      e01[r] = exp2f(s01[r]);
      e11[r] = exp2f(s11[r]);
      sume0 += e00[r] + e10[r];
      sume1 += e01[r] + e11[r];
    }

    // stage e (bf16) into this wave's private LDS region (wave-coherent)
    *(uint2*)&pbuf[w][lm][lh * 4]           = packbf(e00);
    *(uint2*)&pbuf[w][lm][16 + lh * 4]      = packbf(e10);
    *(uint2*)&pbuf[w][16 + lm][lh * 4]      = packbf(e01);
    *(uint2*)&pbuf[w][16 + lm][16 + lh * 4] = packbf(e11);

    union UB { uint4 u; bf16x8 v; } ua, ub;
    {
      const uint2 a0 = *(const uint2*)&pbuf[w][lm][lh * 8];
      const uint2 a1 = *(const uint2*)&pbuf[w][lm][lh * 8 + 4];
      ua.u = make_uint4(a0.x, a0.y, a1.x, a1.y);
      const uint2 b0 = *(const uint2*)&pbuf[w][16 + lm][lh * 8];
      const uint2 b1 = *(const uint2*)&pbuf[w][16 + lm][lh * 8 + 4];
      ub.u = make_uint4(b0.x, b0.y, b1.x, b1.y);
    }

#pragma unroll
    for (int ci = 0; ci < 4; ++ci) {
      racc[0][ci] = __builtin_amdgcn_mfma_f32_16x16x32_bf16(ua.v, xv[ci], racc[0][ci], 0, 0, 0);
      racc[1][ci] = __builtin_amdgcn_mfma_f32_16x16x32_bf16(ub.v, xv[ci], racc[1][ci], 0, 0, 0);
    }
    ha0 = na0; ha1 = na1;
  }

  // row-sum reduce: lanes lh=0..3 partition m
  sume0 += __shfl_xor(sume0, 16); sume0 += __shfl_xor(sume0, 32);
  sume1 += __shfl_xor(sume1, 16); sume1 += __shfl_xor(sume1, 32);
  if (l < 16) { Lp[w][l] = sume0; Lp[w][16 + l] = sume1; }
  __syncthreads();

  float Ls0 = 0.f, Ls1 = 0.f;
#pragma unroll
  for (int ww = 0; ww < NWAVE; ++ww) { Ls0 += Lp[ww][lm]; Ls1 += Lp[ww][16 + lm]; }
  const float Linv0 = 1.0f / Ls0;
  const float Linv1 = 1.0f / Ls1;
  const float blog0 = -log2f(Ls0);   // softmax bias for rows lm
  const float blog1 = -log2f(Ls1);   // and rows 16+lm

  if (tid < 32) {
    float s = 0.f;
#pragma unroll
    for (int ww = 0; ww < NWAVE; ++ww) s += Lp[ww][tid];
    LinvS[tid] = 1.0f / s;
  }

  // reduce partial r across waves
#pragma unroll
  for (int gi = 0; gi < 2; ++gi)
#pragma unroll
    for (int ci = 0; ci < 4; ++ci)
#pragma unroll
      for (int r = 0; r < 4; ++r)
        atomicAdd(&rtile[gi * 16 + lh * 4 + r][ci * 16 + lm], racc[gi][ci][r]);
  __syncthreads();

  // out[b][c][n] = relu(r*Linv + x)  (NT: small, never re-read)
  {
    const int c  = tid >> 3;
    const int j4 = (tid & 7) << 2;
    f32x4 v;
#pragma unroll
    for (int k = 0; k < 4; ++k) v[k] = rtile[j4 + k][c] * LinvS[j4 + k];
    const size_t oo = ((size_t)b * NC + c) * NN + n0 + j4;
    const f32x4 xr = *(const f32x4*)(x + oo);
#pragma unroll
    for (int k = 0; k < 4; ++k) {
      const float t = v[k] + xr[k];
      v[k] = t > 0.f ? t : 0.f;
    }
    __builtin_nontemporal_store(v, (f32x4*)(outp + oo));
  }
  __syncthreads();   // pbuf (aliased into pstage) dead; pstage now safe

  // ---- Phase 2: alpha production ----------------------------------------
  const f32x4 bias0 = {blog0, blog0, blog0, blog0};
  const f32x4 bias1 = {blog1, blog1, blog1, blog1};
  float* aB = alpha + ((size_t)b * NN + n0) * NN;
  const int cw = w << 5;   // this wave's column base within the 256-m window

  // reload ha for phase-2 m layout: wave w owns cols [w*32, w*32+32) per window
  ha0 = *(const bf16x8*)(hB + (size_t)(cw + lm) * NA + lh * 8);
  ha1 = *(const bf16x8*)(hB + (size_t)(cw + 16 + lm) * NA + lh * 8);

  for (int mc = 0; mc < 16; ++mc) {
    const int cur = mc & 1;
    const int m1 = (((mc + 1) & 15) << 8) + cw;   // next window's cols (wraps)
    const bf16x8 na0 = *(const bf16x8*)(hB + (size_t)(m1 + lm) * NA + lh * 8);
    const bf16x8 na1 = *(const bf16x8*)(hB + (size_t)(m1 + 16 + lm) * NA + lh * 8);

    // p = exp2(s + log2(Linv)) : bias folded into MFMA C operand
    const f32x4 s00 = __builtin_amdgcn_mfma_f32_16x16x32_bf16(ha0, gb0, bias0, 0, 0, 0);
    const f32x4 s10 = __builtin_amdgcn_mfma_f32_16x16x32_bf16(ha1, gb0, bias0, 0, 0, 0);
    const f32x4 s01 = __builtin_amdgcn_mfma_f32_16x16x32_bf16(ha0, gb1, bias1, 0, 0, 0);
    const f32x4 s11 = __builtin_amdgcn_mfma_f32_16x16x32_bf16(ha1, gb1, bias1, 0, 0, 0);

    f32x4 p00, p10, p01, p11;
#pragma unroll
    for (int r = 0; r < 4; ++r) {
      p00[r] = exp2f(s00[r]);
      p10[r] = exp2f(s10[r]);
      p01[r] = exp2f(s01[r]);
      p11[r] = exp2f(s11[r]);
    }

    // stage into the block-wide window: [n][cw + m_local]
    *(f32x4*)&pstage[cur][lm]     [cw + lh * 4]      = p00;
    *(f32x4*)&pstage[cur][lm]     [cw + 16 + lh * 4] = p10;
    *(f32x4*)&pstage[cur][16 + lm][cw + lh * 4]      = p01;
    *(f32x4*)&pstage[cur][16 + lm][cw + 16 + lh * 4] = p11;

    // LDS-only barrier: ds_writes visible; NO vmcnt drain (stores fly free)
    asm volatile("s_waitcnt lgkmcnt(0)\n\ts_barrier" ::: "memory");

    // drain: wave w stores rows 4w..4w+3, each ONE contiguous 1KB plain store
    const int mwin = mc << 8;
#pragma unroll
    for (int j = 0; j < 4; ++j) {
      const int row = (w << 2) + j;
      const f32x4 pv = *(const f32x4*)&pstage[cur][row][l * 4];
      *(f32x4*)(aB + (size_t)row * NN + mwin + l * 4) = pv;
    }
    ha0 = na0; ha1 = na1;
  }
}

// ---------------------------------------------------------------------------
extern "C" void kernel_launch(void* const* d_in, const int* in_sizes, int n_in,
                              void* d_out, int out_size, void* d_ws, size_t ws_size,
                              hipStream_t stream) {
  const float* x  = (const float*)d_in[0];
  const float* Wg = (const float*)d_in[1];
  const float* bg = (const float*)d_in[2];
  const float* Wh = (const float*)d_in[3];
  const float* bh = (const float*)d_in[4];

  float* outp  = (float*)d_out;
  float* alpha = outp + (size_t)NB * NC * NN;   // outputs: relu(r) then alpha

  // workspace: gT (2MB) | hqT (2MB) | xfb (4MB)
  ushort* gT  = (ushort*)d_ws;
  ushort* hqT = gT + (size_t)NB * NN * NA;
  ushort* xfb = hqT + (size_t)NB * NN * NA;

  prep_kernel<<<NB * NN / 256, 256, 0, stream>>>(x, Wg, bg, Wh, bh, gT, hqT, xfb);
  attn_kernel<<<NB * (NN / 32), 512, 0, stream>>>(gT, hqT, xfb, x, outp, alpha);
}

// Round 9
// 212.960 us; speedup vs baseline: 1.5628x; 1.2234x over previous
//
#include <hip/hip_runtime.h>
#include <hip/hip_bf16.h>
#include <math.h>

// Sizes fixed by the problem
#define NB 8
#define NC 64
#define NA 32
#define NN 4096
#define NWAVE 8     // waves per block

typedef __attribute__((ext_vector_type(8))) short bf16x8;
typedef __attribute__((ext_vector_type(4))) short bf16x4;
typedef __attribute__((ext_vector_type(4))) float f32x4;

// K=16 bf16 MFMA: A-frag k=(l>>4)*4+j matches the 16x16 score-acc layout
// (m=lh*4+r) exactly -> PV needs NO LDS transpose, NO cross-lane movement.
#if __has_builtin(__builtin_amdgcn_mfma_f32_16x16x16bf16_1k)
  #define HAVE_MFMA16 1
  #define MFMA16(A,B,C) __builtin_amdgcn_mfma_f32_16x16x16bf16_1k(A,B,C,0,0,0)
#elif __has_builtin(__builtin_amdgcn_mfma_f32_16x16x16_bf16)
  #define HAVE_MFMA16 1
  #define MFMA16(A,B,C) __builtin_amdgcn_mfma_f32_16x16x16_bf16(A,B,C,0,0,0)
#else
  #define HAVE_MFMA16 0
#endif

__device__ inline ushort f2bf(float f) {
  union { float f; unsigned u; } v; v.f = f;
  unsigned r = v.u + 0x7fffu + ((v.u >> 16) & 1u);
  return (ushort)(r >> 16);
}

__device__ inline bf16x8 pack8(const f32x4 a, const f32x4 b) {
  union { ushort us[8]; bf16x8 v; } u;
#pragma unroll
  for (int i = 0; i < 4; ++i) { u.us[i] = f2bf(a[i]); u.us[4 + i] = f2bf(b[i]); }
  return u.v;
}

#if HAVE_MFMA16
__device__ inline bf16x4 pk4(const f32x4 p) {
  union { uint u[2]; bf16x4 v; } t;
  asm("v_cvt_pk_bf16_f32 %0, %1, %2" : "=v"(t.u[0]) : "v"(p[0]), "v"(p[1]));
  asm("v_cvt_pk_bf16_f32 %0, %1, %2" : "=v"(t.u[1]) : "v"(p[2]), "v"(p[3]));
  return t.v;
}
#endif

// ---------------------------------------------------------------------------
// Kernel 1: g = (Wg@x + bg) * log2(e), hq = Wh@x + bh.  bf16 outputs:
// gT[b][n][a], hqT[b][n][a] (K=a contiguous);
// xfb2[b][m>>4][c][m&15] = bf16(x) -- 16-m tiles so PV B-frag loads are
// contiguous across c (2 segments/instr instead of 16).
// ---------------------------------------------------------------------------
__global__ __launch_bounds__(256) void prep_kernel(
    const float* __restrict__ x, const float* __restrict__ Wg, const float* __restrict__ bg,
    const float* __restrict__ Wh, const float* __restrict__ bh,
    ushort* __restrict__ gT, ushort* __restrict__ hqT, ushort* __restrict__ xfb2)
{
  __shared__ float wg_s[NA * NC];
  __shared__ float wh_s[NA * NC];
  const int t = threadIdx.x;
  for (int i = t; i < NA * NC; i += 256) { wg_s[i] = Wg[i]; wh_s[i] = Wh[i]; }
  __syncthreads();

  const int gid = blockIdx.x * 256 + t;
  const int b = gid >> 12;
  const int n = gid & (NN - 1);
  const float* xb = x + (size_t)b * NC * NN + n;
  // tiled xfb2 base for this n
  const size_t x2base = (size_t)b * NC * NN + (size_t)(n >> 4) * (NC * 16) + (n & 15);

  float accg[NA], acch[NA];
#pragma unroll
  for (int a = 0; a < NA; ++a) { accg[a] = 0.f; acch[a] = 0.f; }

  for (int c4 = 0; c4 < NC / 4; ++c4) {
    const float xv0 = xb[(size_t)(c4 * 4 + 0) * NN];
    const float xv1 = xb[(size_t)(c4 * 4 + 1) * NN];
    const float xv2 = xb[(size_t)(c4 * 4 + 2) * NN];
    const float xv3 = xb[(size_t)(c4 * 4 + 3) * NN];
    xfb2[x2base + (size_t)(c4 * 4 + 0) * 16] = f2bf(xv0);
    xfb2[x2base + (size_t)(c4 * 4 + 1) * 16] = f2bf(xv1);
    xfb2[x2base + (size_t)(c4 * 4 + 2) * 16] = f2bf(xv2);
    xfb2[x2base + (size_t)(c4 * 4 + 3) * 16] = f2bf(xv3);
#pragma unroll
    for (int a = 0; a < NA; ++a) {
      const float4 wg4 = *(const float4*)&wg_s[a * NC + c4 * 4];
      const float4 wh4 = *(const float4*)&wh_s[a * NC + c4 * 4];
      accg[a] += wg4.x * xv0 + wg4.y * xv1 + wg4.z * xv2 + wg4.w * xv3;
      acch[a] += wh4.x * xv0 + wh4.y * xv1 + wh4.z * xv2 + wh4.w * xv3;
    }
  }

  const float LOG2E = 1.44269504088896340736f;
  ushort og[NA], oh[NA];
#pragma unroll
  for (int a = 0; a < NA; ++a) {
    og[a] = f2bf((accg[a] + bg[a]) * LOG2E);
    oh[a] = f2bf(acch[a] + bh[a]);
  }
  const size_t o = ((size_t)b * NN + n) * NA;
#pragma unroll
  for (int k = 0; k < 4; ++k) {
    uint4 vg, vh;
    vg.x = (uint)og[k*8+0] | ((uint)og[k*8+1] << 16);
    vg.y = (uint)og[k*8+2] | ((uint)og[k*8+3] << 16);
    vg.z = (uint)og[k*8+4] | ((uint)og[k*8+5] << 16);
    vg.w = (uint)og[k*8+6] | ((uint)og[k*8+7] << 16);
    vh.x = (uint)oh[k*8+0] | ((uint)oh[k*8+1] << 16);
    vh.y = (uint)oh[k*8+2] | ((uint)oh[k*8+3] << 16);
    vh.z = (uint)oh[k*8+4] | ((uint)oh[k*8+5] << 16);
    vh.w = (uint)oh[k*8+6] | ((uint)oh[k*8+7] << 16);
    *(uint4*)(gT  + o + k * 8) = vg;
    *(uint4*)(hqT + o + k * 8) = vh;
  }
}

// ---------------------------------------------------------------------------
// Kernel 2 (R4 structure): block = (b, 32-row n-tile), XCD-swizzled; 8 waves,
// wave w owns m in [w*512, (w+1)*512).
// scores(transposed) = mfma(A=hq, B=g): lane=(m=lh*4+r, n=lm).
// Pass A: per-wave partial row sums of exp2 -> LDS -> block Linv.
// Pass B: recompute, p=exp2(s)*Linv -> swizzled f32 LDS tile (store staging);
//   alpha drained as full 128B NT lines; PV:
//   - mfma16 path: p -> bf16 A-frags via v_cvt_pk (acc layout == K16 A-frag
//     layout), B from tiled xfb2 -> no LDS transpose on the chain;
//   - fallback: R4 LDS-read frags + K=32 MFMA.
// Phase 3: LDS atomic r-reduction, transposed coalesced NT epilogue.
// ---------------------------------------------------------------------------
__global__ __launch_bounds__(512, 4) void attn_kernel(
    const ushort* __restrict__ gT, const ushort* __restrict__ hqT,
    const ushort* __restrict__ xfb2, const float* __restrict__ x,
    float* __restrict__ outp, float* __restrict__ alpha)
{
  __shared__ float plds[NWAVE][32][32];   // per-wave p tile, swizzled 16B units
  __shared__ float rtile[32][65];         // block r accumulator [n][c]
  __shared__ float Lp[NWAVE][32];         // per-wave partial row sums

  const int tid = threadIdx.x;
  const int l  = tid & 63;
  const int w  = tid >> 6;
  const int lm = l & 15;
  const int lh = l >> 4;

  // XCD-aware swizzle: grid=1024, 8 XCDs -> contiguous 128 blocks per XCD
  const int wgid = (blockIdx.x & 7) * 128 + (blockIdx.x >> 3);
  const int b  = wgid >> 7;
  const int n0 = (wgid & 127) << 5;

  const ushort* gB  = gT   + (size_t)b * NN * NA;
  const ushort* hB  = hqT  + (size_t)b * NN * NA;
  const ushort* xB2 = xfb2 + (size_t)b * NC * NN;

  bf16x8 gb0 = *(const bf16x8*)(gB + (size_t)(n0 + lm) * NA + lh * 8);
  bf16x8 gb1 = *(const bf16x8*)(gB + (size_t)(n0 + 16 + lm) * NA + lh * 8);
  const int mbase = w << 9;
  bf16x8 ha0 = *(const bf16x8*)(hB + (size_t)(mbase + lm) * NA + lh * 8);
  bf16x8 ha1 = *(const bf16x8*)(hB + (size_t)(mbase + 16 + lm) * NA + lh * 8);

  float* rflat = &rtile[0][0];
  for (int i = tid; i < 32 * 65; i += 512) rflat[i] = 0.f;

  const f32x4 zz = {0.f, 0.f, 0.f, 0.f};

  // ---- Pass A: partial sums of exp2(scores) over this wave's m-chunk ----
  float sume0 = 0.f, sume1 = 0.f;
  for (int mc = 0; mc < 16; ++mc) {
    const int m1 = mbase + (((mc + 1) & 15) << 5);
    const bf16x8 na0 = *(const bf16x8*)(hB + (size_t)(m1 + lm) * NA + lh * 8);
    const bf16x8 na1 = *(const bf16x8*)(hB + (size_t)(m1 + 16 + lm) * NA + lh * 8);

    const f32x4 s00 = __builtin_amdgcn_mfma_f32_16x16x32_bf16(ha0, gb0, zz, 0, 0, 0);
    const f32x4 s10 = __builtin_amdgcn_mfma_f32_16x16x32_bf16(ha1, gb0, zz, 0, 0, 0);
    const f32x4 s01 = __builtin_amdgcn_mfma_f32_16x16x32_bf16(ha0, gb1, zz, 0, 0, 0);
    const f32x4 s11 = __builtin_amdgcn_mfma_f32_16x16x32_bf16(ha1, gb1, zz, 0, 0, 0);
#pragma unroll
    for (int r = 0; r < 4; ++r) {
      sume0 += exp2f(s00[r]) + exp2f(s10[r]);
      sume1 += exp2f(s01[r]) + exp2f(s11[r]);
    }
    ha0 = na0; ha1 = na1;
  }
  sume0 += __shfl_xor(sume0, 16); sume0 += __shfl_xor(sume0, 32);
  sume1 += __shfl_xor(sume1, 16); sume1 += __shfl_xor(sume1, 32);
  if (l < 16) { Lp[w][l] = sume0; Lp[w][16 + l] = sume1; }
  __syncthreads();

  float Ls0 = 0.f, Ls1 = 0.f;
#pragma unroll
  for (int ww = 0; ww < NWAVE; ++ww) { Ls0 += Lp[ww][lm]; Ls1 += Lp[ww][16 + lm]; }
  const float Linv0 = 1.0f / Ls0;
  const float Linv1 = 1.0f / Ls1;

  // ---- Pass B: alpha write + r accumulation ----------------------------
  f32x4 racc[2][4];
#pragma unroll
  for (int gi = 0; gi < 2; ++gi)
#pragma unroll
    for (int ci = 0; ci < 4; ++ci) racc[gi][ci] = zz;

  float* aB = alpha + ((size_t)b * NN + n0) * NN;
  const int k7   = lm & 7;   // swizzle key for rows lm and 16+lm
  const int nrow = l >> 3;   // alpha-store row within 8-row group
  const int uu   = l & 7;    // alpha-store 16B unit

  for (int mc = 0; mc < 16; ++mc) {
    const int m0 = mbase + (mc << 5);
    const int m1 = mbase + (((mc + 1) & 15) << 5);
    const bf16x8 na0 = *(const bf16x8*)(hB + (size_t)(m1 + lm) * NA + lh * 8);
    const bf16x8 na1 = *(const bf16x8*)(hB + (size_t)(m1 + 16 + lm) * NA + lh * 8);

    const f32x4 s00 = __builtin_amdgcn_mfma_f32_16x16x32_bf16(ha0, gb0, zz, 0, 0, 0);
    const f32x4 s10 = __builtin_amdgcn_mfma_f32_16x16x32_bf16(ha1, gb0, zz, 0, 0, 0);
    const f32x4 s01 = __builtin_amdgcn_mfma_f32_16x16x32_bf16(ha0, gb1, zz, 0, 0, 0);
    const f32x4 s11 = __builtin_amdgcn_mfma_f32_16x16x32_bf16(ha1, gb1, zz, 0, 0, 0);

    f32x4 p00, p10, p01, p11;
#pragma unroll
    for (int r = 0; r < 4; ++r) {
      p00[r] = exp2f(s00[r]) * Linv0;
      p10[r] = exp2f(s10[r]) * Linv0;
      p01[r] = exp2f(s01[r]) * Linv1;
      p11[r] = exp2f(s11[r]) * Linv1;
    }

    // scatter p into this wave's swizzled LDS tile (store staging)
    *(f32x4*)&plds[w][lm]     [((lh    ) ^ k7) << 2] = p00;
    *(f32x4*)&plds[w][lm]     [((lh + 4) ^ k7) << 2] = p10;
    *(f32x4*)&plds[w][16 + lm][((lh    ) ^ k7) << 2] = p01;
    *(f32x4*)&plds[w][16 + lm][((lh + 4) ^ k7) << 2] = p11;

    // alpha NT stores: each instr writes 8 rows x full 128B line
#pragma unroll
    for (int j = 0; j < 4; ++j) {
      const int row = j * 8 + nrow;
      const f32x4 pv = *(const f32x4*)&plds[w][row][(uu ^ (row & 7)) << 2];
      __builtin_nontemporal_store(pv, (f32x4*)(aB + (size_t)row * NN + m0 + uu * 4));
    }

    // ---- PV ----
    const int t0 = m0 >> 4;   // 16-m tile index
#if HAVE_MFMA16
    // A-frags straight from the score accumulators (layout identity)
    const bf16x4 A00 = pk4(p00);   // rows lm,    m-half 0
    const bf16x4 A01 = pk4(p10);   // rows lm,    m-half 1
    const bf16x4 A10 = pk4(p01);   // rows 16+lm, m-half 0
    const bf16x4 A11 = pk4(p11);   // rows 16+lm, m-half 1
#pragma unroll
    for (int ci = 0; ci < 4; ++ci) {
      const bf16x4 xv0 = *(const bf16x4*)(xB2 + (size_t)t0       * (NC * 16) + (ci * 16 + lm) * 16 + lh * 4);
      const bf16x4 xv1 = *(const bf16x4*)(xB2 + (size_t)(t0 + 1) * (NC * 16) + (ci * 16 + lm) * 16 + lh * 4);
      racc[0][ci] = MFMA16(A00, xv0, racc[0][ci]);
      racc[0][ci] = MFMA16(A01, xv1, racc[0][ci]);
      racc[1][ci] = MFMA16(A10, xv0, racc[1][ci]);
      racc[1][ci] = MFMA16(A11, xv1, racc[1][ci]);
    }
#else
    // fallback: K=32 A-frags via swizzled LDS reads (R4 path)
    const f32x4 q00 = *(const f32x4*)&plds[w][lm]     [((2 * lh    ) ^ k7) << 2];
    const f32x4 q01 = *(const f32x4*)&plds[w][lm]     [((2 * lh + 1) ^ k7) << 2];
    const f32x4 q10 = *(const f32x4*)&plds[w][16 + lm][((2 * lh    ) ^ k7) << 2];
    const f32x4 q11 = *(const f32x4*)&plds[w][16 + lm][((2 * lh + 1) ^ k7) << 2];
    const bf16x8 pa0 = pack8(q00, q01);
    const bf16x8 pa1 = pack8(q10, q11);
#pragma unroll
    for (int ci = 0; ci < 4; ++ci) {
      const bf16x8 xv = *(const bf16x8*)(xB2 + (size_t)(t0 + (lh >> 1)) * (NC * 16) + (ci * 16 + lm) * 16 + (lh & 1) * 8);
      racc[0][ci] = __builtin_amdgcn_mfma_f32_16x16x32_bf16(pa0, xv, racc[0][ci], 0, 0, 0);
      racc[1][ci] = __builtin_amdgcn_mfma_f32_16x16x32_bf16(pa1, xv, racc[1][ci], 0, 0, 0);
    }
#endif
    ha0 = na0; ha1 = na1;
  }

  // ---- Phase 3: reduce partial r across waves ---------------------------
#pragma unroll
  for (int gi = 0; gi < 2; ++gi)
#pragma unroll
    for (int ci = 0; ci < 4; ++ci)
#pragma unroll
      for (int r = 0; r < 4; ++r)
        atomicAdd(&rtile[gi * 16 + lh * 4 + r][ci * 16 + lm], racc[gi][ci][r]);
  __syncthreads();

  // epilogue: out[b][c][n] = relu(r + x), coalesced NT float4
  const int c  = tid >> 3;
  const int j4 = (tid & 7) << 2;
  f32x4 v;
#pragma unroll
  for (int k = 0; k < 4; ++k) v[k] = rtile[j4 + k][c];
  const size_t oo = ((size_t)b * NC + c) * NN + n0 + j4;
  const f32x4 xr = *(const f32x4*)(x + oo);
#pragma unroll
  for (int k = 0; k < 4; ++k) {
    const float t = v[k] + xr[k];
    v[k] = t > 0.f ? t : 0.f;
  }
  __builtin_nontemporal_store(v, (f32x4*)(outp + oo));
}

// ---------------------------------------------------------------------------
extern "C" void kernel_launch(void* const* d_in, const int* in_sizes, int n_in,
                              void* d_out, int out_size, void* d_ws, size_t ws_size,
                              hipStream_t stream) {
  const float* x  = (const float*)d_in[0];
  const float* Wg = (const float*)d_in[1];
  const float* bg = (const float*)d_in[2];
  const float* Wh = (const float*)d_in[3];
  const float* bh = (const float*)d_in[4];

  float* outp  = (float*)d_out;
  float* alpha = outp + (size_t)NB * NC * NN;   // outputs: relu(r) then alpha

  // workspace: gT (2MB) | hqT (2MB) | xfb2 (4MB)
  ushort* gT   = (ushort*)d_ws;
  ushort* hqT  = gT + (size_t)NB * NN * NA;
  ushort* xfb2 = hqT + (size_t)NB * NN * NA;

  prep_kernel<<<NB * NN / 256, 256, 0, stream>>>(x, Wg, bg, Wh, bh, gT, hqT, xfb2);
  attn_kernel<<<NB * (NN / 32), 512, 0, stream>>>(gT, hqT, xfb2, x, outp, alpha);
}